// Round 5
// baseline (156.343 us; speedup 1.0000x reference)
//
#include <hip/hip_runtime.h>
#include <hip/hip_bf16.h>
#include <stdint.h>

#define B_DIM 4096
#define T_DIM 8
#define IN_DIM 1024
#define OUT_DIM 1024
#define R_DIM 32

#define BM 256
#define BN 256
#define BK 64
#define NKT (IN_DIM / BK)   // 16

typedef __bf16 bf16x8 __attribute__((ext_vector_type(8)));
typedef float  f32x4  __attribute__((ext_vector_type(4)));

#define VMCNT(n) asm volatile("s_waitcnt vmcnt(" #n ")" ::: "memory")
#define LGKM0()  asm volatile("s_waitcnt lgkmcnt(0)" ::: "memory")
#define CFENCE() asm volatile("" ::: "memory")
#define BARRIER() do { CFENCE(); __builtin_amdgcn_s_barrier(); CFENCE(); } while (0)

// ---- helpers --------------------------------------------------------------

// round-to-nearest fp32->bf16, two packed into one u32 (lo in low half)
__device__ __forceinline__ uint32_t pack2_bf16(float a, float b) {
  uint32_t ua = __float_as_uint(a), ub = __float_as_uint(b);
  ua = (ua + 0x7FFFu + ((ua >> 16) & 1u)) >> 16;
  ub = (ub + 0x7FFFu + ((ub >> 16) & 1u)) & 0xFFFF0000u;
  return ua | ub;
}

// async global->LDS, 16B per lane; LDS dest is wave-uniform base + lane*16
__device__ __forceinline__ void gload_lds16(const void* g, void* l) {
  __builtin_amdgcn_global_load_lds(
      (const __attribute__((address_space(1))) void*)(uintptr_t)g,
      (__attribute__((address_space(3))) void*)(uint32_t)(uintptr_t)l,
      16, 0, 0);
}

// stage one 16KB half-tile (128 of 256 rows, 16-row-interleaved: half =
// (row>>4)&1) of B K-tile `ktn` into LDS operand region (32KB).
// LDS dest linear (gload_lds requirement); source chunk pre-swizzled
// (chunk ^= slot&7) so swizzled ds_reads see a conflict-free layout.
__device__ __forceinline__ void stage_half(const uint16_t* gtile, int ktn,
                                           int half, uint8_t* ldsop,
                                           int wave, int lane) {
#pragma unroll
  for (int j = 0; j < 2; ++j) {
    int s = j * 64 + wave * 8 + (lane >> 3);      // slot 0..127 within half
    int c = lane & 7;                             // LDS 16B chunk within row
    int row = (s >> 4) * 32 + half * 16 + (s & 15);
    gload_lds16((const uint8_t*)(gtile + (size_t)row * IN_DIM + ktn * BK) +
                    ((c ^ (s & 7)) << 4),
                ldsop + half * 16384 + j * 8192 + wave * 1024);
  }
}

// fragment reads: slot = (row>>5)*16 + (row&15); chunk = (ks*4+kg) ^ (row&7)
__device__ __forceinline__ bf16x8 lds_frag(const uint8_t* op, int grp,
                                           int par, int ks,
                                           int l15, int kg, int l7) {
  return *(const bf16x8*)(op + par * 16384 + (grp >> 1) * 2048 + l15 * 128 +
                          ((((ks << 2) + kg) ^ l7) << 4));
}

// A fp32 reg-stage: q-pair qp handles rows wave*32 + (qp*2+qq)*8 + (lane>>3),
// floats (lane&7)*8 .. +7 (two dwordx4, h=0/1)
__device__ __forceinline__ void a_issue(const float* gax, int kt, int qp,
                                        float4 ar[2][2]) {
#pragma unroll
  for (int qq = 0; qq < 2; ++qq)
#pragma unroll
    for (int h = 0; h < 2; ++h)
      ar[qq][h] = *(const float4*)(gax +
          (size_t)(qp * 2 + qq) * 8 * (T_DIM * IN_DIM) + kt * BK + h * 4);
}

// cvt + swizzled ds_write: row&7 == lane>>3; global chunk g = lane&7;
// stored chunk = g ^ (row&7). awbase = wave*2048 + (l>>3)*128 + ((g^(l>>3))<<4)
__device__ __forceinline__ void a_cvt_write(uint8_t* nA, int awbase, int qp,
                                            float4 ar[2][2]) {
#pragma unroll
  for (int qq = 0; qq < 2; ++qq) {
    int q = qp * 2 + qq;
    uint4 o;
    o.x = pack2_bf16(ar[qq][0].x, ar[qq][0].y);
    o.y = pack2_bf16(ar[qq][0].z, ar[qq][0].w);
    o.z = pack2_bf16(ar[qq][1].x, ar[qq][1].y);
    o.w = pack2_bf16(ar[qq][1].z, ar[qq][1].w);
    *(uint4*)(nA + ((q >> 1) & 1) * 16384 + (q & 1) * 1024 + awbase) = o;
  }
}

// ---- kernel 1: A1[t][i][k] = sum_j first[t][j] * middle[j][i][k] ----------
__global__ void tt_stage1(const float* __restrict__ first,
                          const float* __restrict__ middle,
                          float* __restrict__ a1) {
  int idx = blockIdx.x * 256 + threadIdx.x;     // t*32768 + i*32 + k
  int t  = idx >> 15;
  int ik = idx & 32767;
  float acc = 0.f;
#pragma unroll
  for (int j = 0; j < R_DIM; ++j)
    acc = fmaf(first[t * R_DIM + j], middle[j * (IN_DIM * R_DIM) + ik], acc);
  a1[idx] = acc;
}

// ---- kernel 2: w_T[t][o][i] = sum_k A1[t][i][k]*task[k][o], bf16 ----------
__global__ __launch_bounds__(256) void tt_stage2(const float* __restrict__ a1,
                                                 const float* __restrict__ task,
                                                 __hip_bfloat16* __restrict__ wT) {
  int bid = blockIdx.x;
  int t  = bid >> 8;
  int ob = (bid >> 4) & 15;
  int ib = bid & 15;
  __shared__ float A1s[64][33];
  __shared__ float Ts[32][64];
  int tid = threadIdx.x;
#pragma unroll
  for (int r = 0; r < 8; ++r) {
    int idx2 = tid + 256 * r;              // 64x32 A1 tile
    int il = idx2 >> 5, k = idx2 & 31;
    A1s[il][k] = a1[t * (IN_DIM * R_DIM) + (ib * 64 + il) * R_DIM + k];
  }
#pragma unroll
  for (int r = 0; r < 8; ++r) {
    int idx2 = tid + 256 * r;              // 32x64 task tile
    int k = idx2 >> 6, ol = idx2 & 63;
    Ts[k][ol] = task[k * OUT_DIM + ob * 64 + ol];
  }
  __syncthreads();
  int il = tid & 63;
  int og = tid >> 6;                        // 0..3
  float acc[16];
#pragma unroll
  for (int r = 0; r < 16; ++r) acc[r] = 0.f;
#pragma unroll
  for (int k = 0; k < 32; ++k) {
    float a = A1s[il][k];
#pragma unroll
    for (int r = 0; r < 16; ++r)
      acc[r] = fmaf(a, Ts[k][og * 16 + r], acc[r]);
  }
#pragma unroll
  for (int r = 0; r < 16; ++r) {
    size_t o = (size_t)ob * 64 + og * 16 + r;
    wT[((size_t)t * OUT_DIM + o) * IN_DIM + ib * 64 + il] = __float2bfloat16(acc[r]);
  }
}

// ---- kernel 3: fused cvt+GEMM, 256x256xBK64, 8-phase counted-vmcnt --------
// A read as fp32 from X directly, converted in-register, ds_written swizzled
// (T14 async-split). B staged via gload_lds (pre-swizzled source). Per iter:
//  P1: ds afr_h0(8)+bfr0(4); glds Bh0(kt+1); vload A-q01(4);  BAR MFMA00 BAR
//  P2: ds bfr1(4);           glds Bh1(kt+1);                  BAR MFMA01 BAR
//  P3: ds afr_h1(8)+bfr0(4); VMCNT(2)[drain Bh0+Aq01, keep Bh1]
//      cvt+dsw q01; vload A-q23(4);                           BAR MFMA10 BAR
//  P4: VMCNT(0)[Bh1 ~2.5ph old, Aq23 ~1ph]; cvt+dsw q23; LGKM0;
//                                                             BAR MFMA11 BAR
// Loads stay in flight across 2-5 barriers (T4 spirit); drains are covered.
__global__ __launch_bounds__(512, 2) void tt_gemm(const float* __restrict__ X,
                                                  const uint16_t* __restrict__ WT,
                                                  float* __restrict__ O) {
  extern __shared__ uint8_t sm[];
  int bid = blockIdx.x;
  const int t  = bid & 7;                 // task == XCD (round-robin dispatch)
  const int l  = bid >> 3;                // 0..63 within task
  const int mt = l >> 2;                  // 0..15
  const int nt = l & 3;                   // n-fastest: A panel L2-shared

  const int tid  = threadIdx.x;
  const int lane = tid & 63;
  const int wave = tid >> 6;              // 0..7
  const int wr = wave >> 2, wc = wave & 3;
  const int wr8 = wr * 8, wc4 = wc * 4;
  const int l15 = lane & 15, l7 = lane & 7, kg = lane >> 4;

  // A fp32 source: rows wave*32 + q*8 + (lane>>3), float cols (lane&7)*8..
  const int arow_in = lane >> 3;
  const float* gax = X +
      ((size_t)(mt * BM + wave * 32 + arow_in) * T_DIM + t) * IN_DIM +
      (lane & 7) * 8;
  const int awbase = wave * 2048 + arow_in * 128 + (((lane & 7) ^ arow_in) << 4);

  const uint16_t* gB = WT + ((size_t)t * OUT_DIM + nt * BN) * IN_DIM;

  f32x4 acc[8][4] = {};
  bf16x8 afr[4][2], bfr0[2][2], bfr1[2][2];
  float4 ar[2][2];

  // ---- prologue: K-tile 0 into buf0 (A via regs in 2 batches), cold drains
  a_issue(gax, 0, 0, ar);
  VMCNT(0);
  a_cvt_write(sm, awbase, 0, ar);
  a_issue(gax, 0, 1, ar);
  VMCNT(0);
  a_cvt_write(sm, awbase, 1, ar);
  stage_half(gB, 0, 0, sm + 32768, wave, lane);
  stage_half(gB, 0, 1, sm + 32768, wave, lane);
  VMCNT(0);
  LGKM0();
  BARRIER();

#pragma unroll 2
  for (int kt = 0; kt < NKT - 1; ++kt) {
    const int P = kt & 1;
    const uint8_t* bA = sm + P * 65536;
    const uint8_t* bB = bA + 32768;
    uint8_t* nA = sm + (P ^ 1) * 65536;
    uint8_t* nB = nA + 32768;

    // ===== P1: (mp0, np0)
#pragma unroll
    for (int mo = 0; mo < 4; ++mo)
#pragma unroll
      for (int ks = 0; ks < 2; ++ks)
        afr[mo][ks] = lds_frag(bA, wr8 + mo * 2, 0, ks, l15, kg, l7);
#pragma unroll
    for (int no = 0; no < 2; ++no)
#pragma unroll
      for (int ks = 0; ks < 2; ++ks)
        bfr0[no][ks] = lds_frag(bB, wc4 + no * 2, 0, ks, l15, kg, l7);
    stage_half(gB, kt + 1, 0, nB, wave, lane);    // Bh0: 2 gloads
    a_issue(gax, kt + 1, 0, ar);                  // A q01: 4 loads
    BARRIER();
    __builtin_amdgcn_s_setprio(1);
#pragma unroll
    for (int mo = 0; mo < 4; ++mo)
#pragma unroll
      for (int no = 0; no < 2; ++no)
#pragma unroll
        for (int ks = 0; ks < 2; ++ks)
          acc[mo * 2][no * 2] = __builtin_amdgcn_mfma_f32_16x16x32_bf16(
              afr[mo][ks], bfr0[no][ks], acc[mo * 2][no * 2], 0, 0, 0);
    __builtin_amdgcn_s_setprio(0);
    BARRIER();

    // ===== P2: (mp0, np1)
#pragma unroll
    for (int no = 0; no < 2; ++no)
#pragma unroll
      for (int ks = 0; ks < 2; ++ks)
        bfr1[no][ks] = lds_frag(bB, wc4 + no * 2 + 1, 1, ks, l15, kg, l7);
    stage_half(gB, kt + 1, 1, nB, wave, lane);    // Bh1: 2 gloads
    BARRIER();
    __builtin_amdgcn_s_setprio(1);
#pragma unroll
    for (int mo = 0; mo < 4; ++mo)
#pragma unroll
      for (int no = 0; no < 2; ++no)
#pragma unroll
        for (int ks = 0; ks < 2; ++ks)
          acc[mo * 2][no * 2 + 1] = __builtin_amdgcn_mfma_f32_16x16x32_bf16(
              afr[mo][ks], bfr1[no][ks], acc[mo * 2][no * 2 + 1], 0, 0, 0);
    __builtin_amdgcn_s_setprio(0);
    BARRIER();

    // ===== P3: (mp1, np0)  [re-read bfr0 h0: shortens its live range]
#pragma unroll
    for (int mo = 0; mo < 4; ++mo)
#pragma unroll
      for (int ks = 0; ks < 2; ++ks)
        afr[mo][ks] = lds_frag(bA, wr8 + mo * 2 + 1, 1, ks, l15, kg, l7);
#pragma unroll
    for (int no = 0; no < 2; ++no)
#pragma unroll
      for (int ks = 0; ks < 2; ++ks)
        bfr0[no][ks] = lds_frag(bB, wc4 + no * 2, 0, ks, l15, kg, l7);
    VMCNT(2);                       // drain Bh0(kt+1)+A-q01; keep Bh1 flying
    a_cvt_write(nA, awbase, 0, ar);
    a_issue(gax, kt + 1, 1, ar);                  // A q23: 4 loads
    BARRIER();
    __builtin_amdgcn_s_setprio(1);
#pragma unroll
    for (int mo = 0; mo < 4; ++mo)
#pragma unroll
      for (int no = 0; no < 2; ++no)
#pragma unroll
        for (int ks = 0; ks < 2; ++ks)
          acc[mo * 2 + 1][no * 2] = __builtin_amdgcn_mfma_f32_16x16x32_bf16(
              afr[mo][ks], bfr0[no][ks], acc[mo * 2 + 1][no * 2], 0, 0, 0);
    __builtin_amdgcn_s_setprio(0);
    BARRIER();

    // ===== P4: (mp1, np1)
    VMCNT(0);                       // Bh1 ~2.5 phases old, A-q23 ~1 phase
    a_cvt_write(nA, awbase, 1, ar);
    LGKM0();                        // A ds_writes visible before barrier
    BARRIER();
    __builtin_amdgcn_s_setprio(1);
#pragma unroll
    for (int mo = 0; mo < 4; ++mo)
#pragma unroll
      for (int no = 0; no < 2; ++no)
#pragma unroll
        for (int ks = 0; ks < 2; ++ks)
          acc[mo * 2 + 1][no * 2 + 1] = __builtin_amdgcn_mfma_f32_16x16x32_bf16(
              afr[mo][ks], bfr1[no][ks], acc[mo * 2 + 1][no * 2 + 1], 0, 0, 0);
    __builtin_amdgcn_s_setprio(0);
    BARRIER();
  }

  // ---- tail iteration kt = NKT-1 (P=1), no staging
  {
    const uint8_t* bA = sm + 65536;
    const uint8_t* bB = bA + 32768;
#pragma unroll
    for (int mo = 0; mo < 4; ++mo)
#pragma unroll
      for (int ks = 0; ks < 2; ++ks)
        afr[mo][ks] = lds_frag(bA, wr8 + mo * 2, 0, ks, l15, kg, l7);
#pragma unroll
    for (int no = 0; no < 2; ++no)
#pragma unroll
      for (int ks = 0; ks < 2; ++ks)
        bfr0[no][ks] = lds_frag(bB, wc4 + no * 2, 0, ks, l15, kg, l7);
#pragma unroll
    for (int no = 0; no < 2; ++no)
#pragma unroll
      for (int ks = 0; ks < 2; ++ks)
        bfr1[no][ks] = lds_frag(bB, wc4 + no * 2 + 1, 1, ks, l15, kg, l7);
#pragma unroll
    for (int mo = 0; mo < 4; ++mo)
#pragma unroll
      for (int no = 0; no < 2; ++no)
#pragma unroll
        for (int ks = 0; ks < 2; ++ks)
          acc[mo * 2][no * 2] = __builtin_amdgcn_mfma_f32_16x16x32_bf16(
              afr[mo][ks], bfr0[no][ks], acc[mo * 2][no * 2], 0, 0, 0);
#pragma unroll
    for (int mo = 0; mo < 4; ++mo)
#pragma unroll
      for (int no = 0; no < 2; ++no)
#pragma unroll
        for (int ks = 0; ks < 2; ++ks)
          acc[mo * 2][no * 2 + 1] = __builtin_amdgcn_mfma_f32_16x16x32_bf16(
              afr[mo][ks], bfr1[no][ks], acc[mo * 2][no * 2 + 1], 0, 0, 0);
#pragma unroll
    for (int mo = 0; mo < 4; ++mo)
#pragma unroll
      for (int ks = 0; ks < 2; ++ks)
        afr[mo][ks] = lds_frag(bA, wr8 + mo * 2 + 1, 1, ks, l15, kg, l7);
#pragma unroll
    for (int mo = 0; mo < 4; ++mo)
#pragma unroll
      for (int no = 0; no < 2; ++no)
#pragma unroll
        for (int ks = 0; ks < 2; ++ks) {
          acc[mo * 2 + 1][no * 2] = __builtin_amdgcn_mfma_f32_16x16x32_bf16(
              afr[mo][ks], bfr0[no][ks], acc[mo * 2 + 1][no * 2], 0, 0, 0);
          acc[mo * 2 + 1][no * 2 + 1] = __builtin_amdgcn_mfma_f32_16x16x32_bf16(
              afr[mo][ks], bfr1[no][ks], acc[mo * 2 + 1][no * 2 + 1], 0, 0, 0);
        }
  }

  // ---- epilogue: C/D layout col=lane&15, row=(lane>>4)*4+j (m89-verified)
  const int crow0 = mt * BM + wr * 128 + (lane >> 4) * 4;
  const int ccol0 = nt * BN + wc * 64 + (lane & 15);
#pragma unroll
  for (int m = 0; m < 8; ++m) {
#pragma unroll
    for (int j = 0; j < 4; ++j) {
      size_t rowoff =
          ((size_t)(crow0 + m * 16 + j) * T_DIM + t) * OUT_DIM + ccol0;
#pragma unroll
      for (int n = 0; n < 4; ++n)
        O[rowoff + n * 16] = acc[m][n][j];
    }
  }
}

// ---- host ------------------------------------------------------------------
extern "C" void kernel_launch(void* const* d_in, const int* in_sizes, int n_in,
                              void* d_out, int out_size, void* d_ws, size_t ws_size,
                              hipStream_t stream) {
  const float* x      = (const float*)d_in[0];
  const float* first  = (const float*)d_in[1];
  const float* middle = (const float*)d_in[2];
  const float* task   = (const float*)d_in[3];
  float* out = (float*)d_out;

  // ws: a1 fp32 1MB @0; wT bf16 16MB @1MB
  float* a1 = (float*)d_ws;
  __hip_bfloat16* wT = (__hip_bfloat16*)((uint8_t*)d_ws + (1u << 20));

  hipFuncSetAttribute((const void*)tt_gemm,
                      hipFuncAttributeMaxDynamicSharedMemorySize, 131072);

  tt_stage1<<<(T_DIM * IN_DIM * R_DIM) / 256, 256, 0, stream>>>(first, middle, a1);
  tt_stage2<<<T_DIM * 16 * 16, 256, 0, stream>>>(a1, task, wT);
  tt_gemm<<<T_DIM * (B_DIM / BM) * (OUT_DIM / BN), 512, 131072, stream>>>(
      x, (const uint16_t*)wT, out);
}

// Round 6
// 127.345 us; speedup vs baseline: 1.2277x; 1.2277x over previous
//
#include <hip/hip_runtime.h>
#include <hip/hip_bf16.h>
#include <stdint.h>

#define B_DIM 4096
#define T_DIM 8
#define IN_DIM 1024
#define OUT_DIM 1024
#define R_DIM 32

#define BM 256
#define BN 256
#define BK 64
#define NKT (IN_DIM / BK)   // 16

typedef __bf16 bf16x8 __attribute__((ext_vector_type(8)));
typedef float  f32x4  __attribute__((ext_vector_type(4)));

#define VMCNT(n) asm volatile("s_waitcnt vmcnt(" #n ")" ::: "memory")
#define LGKM0()  asm volatile("s_waitcnt lgkmcnt(0)" ::: "memory")
#define CFENCE() asm volatile("" ::: "memory")
#define BARRIER() do { CFENCE(); __builtin_amdgcn_s_barrier(); CFENCE(); } while (0)

// ---- helpers --------------------------------------------------------------

// round-to-nearest fp32->bf16, two packed into one u32 (lo in low half)
__device__ __forceinline__ uint32_t pack2_bf16(float a, float b) {
  uint32_t ua = __float_as_uint(a), ub = __float_as_uint(b);
  ua = (ua + 0x7FFFu + ((ua >> 16) & 1u)) >> 16;
  ub = (ub + 0x7FFFu + ((ub >> 16) & 1u)) & 0xFFFF0000u;
  return ua | ub;
}

// async global->LDS, 16B per lane; LDS dest is wave-uniform base + lane*16
__device__ __forceinline__ void gload_lds16(const void* g, void* l) {
  __builtin_amdgcn_global_load_lds(
      (const __attribute__((address_space(1))) void*)(uintptr_t)g,
      (__attribute__((address_space(3))) void*)(uint32_t)(uintptr_t)l,
      16, 0, 0);
}

// stage one 16KB half-tile (128 of 256 rows, 16-row-interleaved: half =
// (row>>4)&1) of B K-tile `ktn` into LDS operand region (32KB).
// LDS dest linear (gload_lds requirement); source chunk pre-swizzled
// (chunk ^= slot&7) so swizzled ds_reads see a conflict-free layout.
__device__ __forceinline__ void stage_half(const uint16_t* gtile, int ktn,
                                           int half, uint8_t* ldsop,
                                           int wave, int lane) {
#pragma unroll
  for (int j = 0; j < 2; ++j) {
    int s = j * 64 + wave * 8 + (lane >> 3);      // slot 0..127 within half
    int c = lane & 7;                             // LDS 16B chunk within row
    int row = (s >> 4) * 32 + half * 16 + (s & 15);
    gload_lds16((const uint8_t*)(gtile + (size_t)row * IN_DIM + ktn * BK) +
                    ((c ^ (s & 7)) << 4),
                ldsop + half * 16384 + j * 8192 + wave * 1024);
  }
}

// fragment reads: slot = (row>>5)*16 + (row&15); chunk = (ks*4+kg) ^ (row&7)
__device__ __forceinline__ bf16x8 lds_frag(const uint8_t* op, int grp,
                                           int par, int ks,
                                           int l15, int kg, int l7) {
  return *(const bf16x8*)(op + par * 16384 + (grp >> 1) * 2048 + l15 * 128 +
                          ((((ks << 2) + kg) ^ l7) << 4));
}

// A fp32 reg-stage: q-pair qp handles rows wave*32 + (qp*2+qq)*8 + (lane>>3),
// floats (lane&7)*8 .. +7 (two dwordx4, h=0/1)
__device__ __forceinline__ void a_issue(const float* gax, int kt, int qp,
                                        float4 ar[2][2]) {
#pragma unroll
  for (int qq = 0; qq < 2; ++qq)
#pragma unroll
    for (int h = 0; h < 2; ++h)
      ar[qq][h] = *(const float4*)(gax +
          (size_t)(qp * 2 + qq) * 8 * (T_DIM * IN_DIM) + kt * BK + h * 4);
}

// cvt + swizzled ds_write: row&7 == lane>>3; global chunk g = lane&7;
// stored chunk = g ^ (row&7). awbase = wave*2048 + (l>>3)*128 + ((g^(l>>3))<<4)
__device__ __forceinline__ void a_cvt_write(uint8_t* nA, int awbase, int qp,
                                            float4 ar[2][2]) {
#pragma unroll
  for (int qq = 0; qq < 2; ++qq) {
    int q = qp * 2 + qq;
    uint4 o;
    o.x = pack2_bf16(ar[qq][0].x, ar[qq][0].y);
    o.y = pack2_bf16(ar[qq][0].z, ar[qq][0].w);
    o.z = pack2_bf16(ar[qq][1].x, ar[qq][1].y);
    o.w = pack2_bf16(ar[qq][1].z, ar[qq][1].w);
    *(uint4*)(nA + ((q >> 1) & 1) * 16384 + (q & 1) * 1024 + awbase) = o;
  }
}

// ---- kernel 1: A1[t][i][k] = sum_j first[t][j] * middle[j][i][k] ----------
__global__ void tt_stage1(const float* __restrict__ first,
                          const float* __restrict__ middle,
                          float* __restrict__ a1) {
  int idx = blockIdx.x * 256 + threadIdx.x;     // t*32768 + i*32 + k
  int t  = idx >> 15;
  int ik = idx & 32767;
  float acc = 0.f;
#pragma unroll
  for (int j = 0; j < R_DIM; ++j)
    acc = fmaf(first[t * R_DIM + j], middle[j * (IN_DIM * R_DIM) + ik], acc);
  a1[idx] = acc;
}

// ---- kernel 2: w_T[t][o][i] = sum_k A1[t][i][k]*task[k][o], bf16 ----------
__global__ __launch_bounds__(256) void tt_stage2(const float* __restrict__ a1,
                                                 const float* __restrict__ task,
                                                 __hip_bfloat16* __restrict__ wT) {
  int bid = blockIdx.x;
  int t  = bid >> 8;
  int ob = (bid >> 4) & 15;
  int ib = bid & 15;
  __shared__ float A1s[64][33];
  __shared__ float Ts[32][64];
  int tid = threadIdx.x;
#pragma unroll
  for (int r = 0; r < 8; ++r) {
    int idx2 = tid + 256 * r;              // 64x32 A1 tile
    int il = idx2 >> 5, k = idx2 & 31;
    A1s[il][k] = a1[t * (IN_DIM * R_DIM) + (ib * 64 + il) * R_DIM + k];
  }
#pragma unroll
  for (int r = 0; r < 8; ++r) {
    int idx2 = tid + 256 * r;              // 32x64 task tile
    int k = idx2 >> 6, ol = idx2 & 63;
    Ts[k][ol] = task[k * OUT_DIM + ob * 64 + ol];
  }
  __syncthreads();
  int il = tid & 63;
  int og = tid >> 6;                        // 0..3
  float acc[16];
#pragma unroll
  for (int r = 0; r < 16; ++r) acc[r] = 0.f;
#pragma unroll
  for (int k = 0; k < 32; ++k) {
    float a = A1s[il][k];
#pragma unroll
    for (int r = 0; r < 16; ++r)
      acc[r] = fmaf(a, Ts[k][og * 16 + r], acc[r]);
  }
#pragma unroll
  for (int r = 0; r < 16; ++r) {
    size_t o = (size_t)ob * 64 + og * 16 + r;
    wT[((size_t)t * OUT_DIM + o) * IN_DIM + ib * 64 + il] = __float2bfloat16(acc[r]);
  }
}

// ---- kernel 3: fused cvt+GEMM, 256x256xBK64, 8-phase, 2-deep A pipeline ---
// A read fp32 from X, cvt in-register, ds_written swizzled. B via gload_lds.
// Per-wave FIFO (12 loads/iter): enter P1 with [A(kt+1,q01)4, A(kt+1,q23)4].
//  P1: ds afr_h0(8)+bfr0(4); VMCNT(4) cvt+dsw q01->nA;
//      glds B(kt+1) h0+h1(4); issue A(kt+2,q01)(4);   BAR MFMA00 BAR
//  P2: ds bfr1(4);                                    BAR MFMA01 BAR
//  P3: ds afr_h1(8)+bfr0(4); VMCNT(8) cvt+dsw q23->nA;
//      issue A(kt+2,q23)(4);                          BAR MFMA10 BAR
//  P4: VMCNT(8) [B(kt+1) ready]; LGKM0;               BAR MFMA11 BAR
// Covers: A q01/q23 = 4 phases, B = 3 phases; never drain to 0 (T4).
__global__ __launch_bounds__(512, 2) void tt_gemm(const float* __restrict__ X,
                                                  const uint16_t* __restrict__ WT,
                                                  float* __restrict__ O) {
  extern __shared__ uint8_t sm[];
  int bid = blockIdx.x;
  const int t  = bid & 7;                 // task == XCD (round-robin dispatch)
  const int l  = bid >> 3;                // 0..63 within task
  const int mt = l >> 2;                  // 0..15
  const int nt = l & 3;                   // n-fastest: A panel L2-shared

  const int tid  = threadIdx.x;
  const int lane = tid & 63;
  const int wave = tid >> 6;              // 0..7
  const int wr = wave >> 2, wc = wave & 3;
  const int wr8 = wr * 8, wc4 = wc * 4;
  const int l15 = lane & 15, l7 = lane & 7, kg = lane >> 4;

  // A fp32 source: rows wave*32 + q*8 + (lane>>3), float cols (lane&7)*8..
  const int arow_in = lane >> 3;
  const float* gax = X +
      ((size_t)(mt * BM + wave * 32 + arow_in) * T_DIM + t) * IN_DIM +
      (lane & 7) * 8;
  const int awbase = wave * 2048 + arow_in * 128 + (((lane & 7) ^ arow_in) << 4);

  const uint16_t* gB = WT + ((size_t)t * OUT_DIM + nt * BN) * IN_DIM;

  f32x4 acc[8][4] = {};
  bf16x8 afr[4][2], bfr0[2][2], bfr1[2][2];
  float4 arX[2][2], arY[2][2];

  // ---- prologue: K-tile 0 into buf0; prime 2-deep A regs with tile 1
  a_issue(gax, 0, 0, arX);                        // 4
  a_issue(gax, 0, 1, arY);                        // 4
  stage_half(gB, 0, 0, sm + 32768, wave, lane);   // 2
  stage_half(gB, 0, 1, sm + 32768, wave, lane);   // 2
  VMCNT(8);                                       // A(0,q01) done
  a_cvt_write(sm, awbase, 0, arX);
  VMCNT(4);                                       // A(0,q23) done
  a_cvt_write(sm, awbase, 1, arY);
  a_issue(gax, 1, 0, arX);                        // 4
  a_issue(gax, 1, 1, arY);                        // 4
  VMCNT(8);                                       // B(0) done; A(1) in flight
  LGKM0();
  BARRIER();

  for (int kt = 0; kt < NKT - 1; ++kt) {
    const int P = kt & 1;
    const uint8_t* bA = sm + P * 65536;
    const uint8_t* bB = bA + 32768;
    uint8_t* nA = sm + (P ^ 1) * 65536;
    uint8_t* nB = nA + 32768;
    const int kt2 = (kt + 2 < NKT) ? (kt + 2) : (NKT - 1);  // clamp: uniform counts

    // ===== P1: (mp0, np0)
#pragma unroll
    for (int mo = 0; mo < 4; ++mo)
#pragma unroll
      for (int ks = 0; ks < 2; ++ks)
        afr[mo][ks] = lds_frag(bA, wr8 + mo * 2, 0, ks, l15, kg, l7);
#pragma unroll
    for (int no = 0; no < 2; ++no)
#pragma unroll
      for (int ks = 0; ks < 2; ++ks)
        bfr0[no][ks] = lds_frag(bB, wc4 + no * 2, 0, ks, l15, kg, l7);
    VMCNT(4);                           // A(kt+1,q01) ready (4-phase cover)
    a_cvt_write(nA, awbase, 0, arX);
    stage_half(gB, kt + 1, 0, nB, wave, lane);    // B both halves: 4 glds
    stage_half(gB, kt + 1, 1, nB, wave, lane);
    a_issue(gax, kt2, 0, arX);                    // A(kt+2,q01): 4 loads
    BARRIER();
    __builtin_amdgcn_s_setprio(1);
#pragma unroll
    for (int mo = 0; mo < 4; ++mo)
#pragma unroll
      for (int no = 0; no < 2; ++no)
#pragma unroll
        for (int ks = 0; ks < 2; ++ks)
          acc[mo * 2][no * 2] = __builtin_amdgcn_mfma_f32_16x16x32_bf16(
              afr[mo][ks], bfr0[no][ks], acc[mo * 2][no * 2], 0, 0, 0);
    __builtin_amdgcn_s_setprio(0);
    BARRIER();

    // ===== P2: (mp0, np1)
#pragma unroll
    for (int no = 0; no < 2; ++no)
#pragma unroll
      for (int ks = 0; ks < 2; ++ks)
        bfr1[no][ks] = lds_frag(bB, wc4 + no * 2 + 1, 1, ks, l15, kg, l7);
    BARRIER();
    __builtin_amdgcn_s_setprio(1);
#pragma unroll
    for (int mo = 0; mo < 4; ++mo)
#pragma unroll
      for (int no = 0; no < 2; ++no)
#pragma unroll
        for (int ks = 0; ks < 2; ++ks)
          acc[mo * 2][no * 2 + 1] = __builtin_amdgcn_mfma_f32_16x16x32_bf16(
              afr[mo][ks], bfr1[no][ks], acc[mo * 2][no * 2 + 1], 0, 0, 0);
    __builtin_amdgcn_s_setprio(0);
    BARRIER();

    // ===== P3: (mp1, np0)  [re-read bfr0 h0: shortens its live range]
#pragma unroll
    for (int mo = 0; mo < 4; ++mo)
#pragma unroll
      for (int ks = 0; ks < 2; ++ks)
        afr[mo][ks] = lds_frag(bA, wr8 + mo * 2 + 1, 1, ks, l15, kg, l7);
#pragma unroll
    for (int no = 0; no < 2; ++no)
#pragma unroll
      for (int ks = 0; ks < 2; ++ks)
        bfr0[no][ks] = lds_frag(bB, wc4 + no * 2, 0, ks, l15, kg, l7);
    VMCNT(8);                           // A(kt+1,q23) ready (4-phase cover)
    a_cvt_write(nA, awbase, 1, arY);
    a_issue(gax, kt2, 1, arY);                    // A(kt+2,q23): 4 loads
    BARRIER();
    __builtin_amdgcn_s_setprio(1);
#pragma unroll
    for (int mo = 0; mo < 4; ++mo)
#pragma unroll
      for (int no = 0; no < 2; ++no)
#pragma unroll
        for (int ks = 0; ks < 2; ++ks)
          acc[mo * 2 + 1][no * 2] = __builtin_amdgcn_mfma_f32_16x16x32_bf16(
              afr[mo][ks], bfr0[no][ks], acc[mo * 2 + 1][no * 2], 0, 0, 0);
    __builtin_amdgcn_s_setprio(0);
    BARRIER();

    // ===== P4: (mp1, np1)
    VMCNT(8);                           // B(kt+1) ready (3-phase cover)
    LGKM0();                            // A ds_writes (P1,P3) visible
    BARRIER();
    __builtin_amdgcn_s_setprio(1);
#pragma unroll
    for (int mo = 0; mo < 4; ++mo)
#pragma unroll
      for (int no = 0; no < 2; ++no)
#pragma unroll
        for (int ks = 0; ks < 2; ++ks)
          acc[mo * 2 + 1][no * 2 + 1] = __builtin_amdgcn_mfma_f32_16x16x32_bf16(
              afr[mo][ks], bfr1[no][ks], acc[mo * 2 + 1][no * 2 + 1], 0, 0, 0);
    __builtin_amdgcn_s_setprio(0);
    BARRIER();
  }

  // ---- tail iteration kt = NKT-1 (P=1), no staging, no waits
  {
    const uint8_t* bA = sm + 65536;
    const uint8_t* bB = bA + 32768;
#pragma unroll
    for (int mo = 0; mo < 4; ++mo)
#pragma unroll
      for (int ks = 0; ks < 2; ++ks)
        afr[mo][ks] = lds_frag(bA, wr8 + mo * 2, 0, ks, l15, kg, l7);
#pragma unroll
    for (int no = 0; no < 2; ++no)
#pragma unroll
      for (int ks = 0; ks < 2; ++ks)
        bfr0[no][ks] = lds_frag(bB, wc4 + no * 2, 0, ks, l15, kg, l7);
#pragma unroll
    for (int no = 0; no < 2; ++no)
#pragma unroll
      for (int ks = 0; ks < 2; ++ks)
        bfr1[no][ks] = lds_frag(bB, wc4 + no * 2 + 1, 1, ks, l15, kg, l7);
#pragma unroll
    for (int mo = 0; mo < 4; ++mo)
#pragma unroll
      for (int no = 0; no < 2; ++no)
#pragma unroll
        for (int ks = 0; ks < 2; ++ks)
          acc[mo * 2][no * 2] = __builtin_amdgcn_mfma_f32_16x16x32_bf16(
              afr[mo][ks], bfr0[no][ks], acc[mo * 2][no * 2], 0, 0, 0);
#pragma unroll
    for (int mo = 0; mo < 4; ++mo)
#pragma unroll
      for (int no = 0; no < 2; ++no)
#pragma unroll
        for (int ks = 0; ks < 2; ++ks)
          acc[mo * 2][no * 2 + 1] = __builtin_amdgcn_mfma_f32_16x16x32_bf16(
              afr[mo][ks], bfr1[no][ks], acc[mo * 2][no * 2 + 1], 0, 0, 0);
#pragma unroll
    for (int mo = 0; mo < 4; ++mo)
#pragma unroll
      for (int ks = 0; ks < 2; ++ks)
        afr[mo][ks] = lds_frag(bA, wr8 + mo * 2 + 1, 1, ks, l15, kg, l7);
#pragma unroll
    for (int mo = 0; mo < 4; ++mo)
#pragma unroll
      for (int no = 0; no < 2; ++no)
#pragma unroll
        for (int ks = 0; ks < 2; ++ks) {
          acc[mo * 2 + 1][no * 2] = __builtin_amdgcn_mfma_f32_16x16x32_bf16(
              afr[mo][ks], bfr0[no][ks], acc[mo * 2 + 1][no * 2], 0, 0, 0);
          acc[mo * 2 + 1][no * 2 + 1] = __builtin_amdgcn_mfma_f32_16x16x32_bf16(
              afr[mo][ks], bfr1[no][ks], acc[mo * 2 + 1][no * 2 + 1], 0, 0, 0);
        }
  }

  // ---- epilogue: C/D layout col=lane&15, row=(lane>>4)*4+j (m89-verified)
  const int crow0 = mt * BM + wr * 128 + (lane >> 4) * 4;
  const int ccol0 = nt * BN + wc * 64 + (lane & 15);
#pragma unroll
  for (int m = 0; m < 8; ++m) {
#pragma unroll
    for (int j = 0; j < 4; ++j) {
      size_t rowoff =
          ((size_t)(crow0 + m * 16 + j) * T_DIM + t) * OUT_DIM + ccol0;
#pragma unroll
      for (int n = 0; n < 4; ++n)
        O[rowoff + n * 16] = acc[m][n][j];
    }
  }
}

// ---- host ------------------------------------------------------------------
extern "C" void kernel_launch(void* const* d_in, const int* in_sizes, int n_in,
                              void* d_out, int out_size, void* d_ws, size_t ws_size,
                              hipStream_t stream) {
  const float* x      = (const float*)d_in[0];
  const float* first  = (const float*)d_in[1];
  const float* middle = (const float*)d_in[2];
  const float* task   = (const float*)d_in[3];
  float* out = (float*)d_out;

  // ws: a1 fp32 1MB @0; wT bf16 16MB @1MB
  float* a1 = (float*)d_ws;
  __hip_bfloat16* wT = (__hip_bfloat16*)((uint8_t*)d_ws + (1u << 20));

  hipFuncSetAttribute((const void*)tt_gemm,
                      hipFuncAttributeMaxDynamicSharedMemorySize, 131072);

  tt_stage1<<<(T_DIM * IN_DIM * R_DIM) / 256, 256, 0, stream>>>(first, middle, a1);
  tt_stage2<<<T_DIM * 16 * 16, 256, 0, stream>>>(a1, task, wT);
  tt_gemm<<<T_DIM * (B_DIM / BM) * (OUT_DIM / BN), 512, 131072, stream>>>(
      x, (const uint16_t*)wT, out);
}